// Round 11
// baseline (671.611 us; speedup 1.0000x reference)
//
#include <hip/hip_runtime.h>
#include <hip/hip_bf16.h>

#define BN 32
#define CC 128
#define NN 2025
#define KK 9
#define NGROUP 4
#define CPG 32
#define GN_EPS 1e-5f
#define ROWS_TOTAL (BN * NN)   // 64800

typedef _Float16 f16;
typedef __attribute__((ext_vector_type(8))) _Float16 f16x8;
typedef __attribute__((ext_vector_type(4))) _Float16 f16x4;
typedef __attribute__((ext_vector_type(4))) float f32x4;

#define S28 3.725290298461914e-09f   // 2^-28  (xh*wh)
#define S40 9.094947017729282e-13f   // 2^-40  (xh*wl + xl*wh)
#define S26 1.4901161193847656e-08f  // 2^-26  (vh*wh, layer2)
#define S38 3.637978807091713e-12f   // 2^-38  (vh*wl + vl*wh, layer2)
#define RH  6.103515625e-05f         // 2^-14
#define RL  1.4901161193847656e-08f  // 2^-26

#define T0F 0.17f                    // survivor threshold (9th-best ~0.23, min ~0.19)
#define CAP 100                      // per-row survivor capacity (mean ~55, max ~95; overflow -> exact fallback)

// ---------------- Kernel 1: L2 normalize -> scaled f16 split (R10 transpose version) ----------------
__global__ __launch_bounds__(256) void k_normalize(const float* __restrict__ x,
                                                   f16* __restrict__ xh, f16* __restrict__ xl) {
    __shared__ float tile[128][65];
    const int b  = blockIdx.y;
    const int n0 = blockIdx.x * 64;
    const int t  = threadIdx.x;
    const int w  = t >> 6;
    const int lane = t & 63;
    const int gn_ld = min(n0 + lane, NN - 1);   // tail clamp (dup value, never stored)

    for (int it = 0; it < 32; ++it) {
        int c = it * 4 + w;
        tile[c][lane] = x[((size_t)(b * CC + c)) * NN + gn_ld];
    }
    __syncthreads();

    for (int i = 0; i < 16; ++i) {
        int n  = w * 16 + i;
        int gn = n0 + n;
        if (gn < NN) {
            float v0 = tile[lane][n];
            float v1 = tile[lane + 64][n];
            float ss = v0 * v0 + v1 * v1;
#pragma unroll
            for (int off = 32; off > 0; off >>= 1) ss += __shfl_xor(ss, off);
            float s = 1.0f / fmaxf(sqrtf(ss), 1e-12f);
            v0 *= s; v1 *= s;
            float w0 = v0 * 16384.0f, w1 = v1 * 16384.0f;
            f16 h0 = (f16)w0, h1 = (f16)w1;
            f16 l0 = (f16)((w0 - (float)h0) * 4096.0f);
            f16 l1 = (f16)((w1 - (float)h1) * 4096.0f);
            size_t base = (size_t)(b * NN + gn) * CC;
            xh[base + lane] = h0;  xh[base + lane + 64] = h1;
            xl[base + lane] = l0;  xl[base + lane + 64] = l1;
        }
    }
}

// top-9 insert: (value desc, index asc) ordering; order-independent tie rules — EXACT
__device__ __forceinline__ void ins9(float cand, int m, float* v, int* ix,
                                     float& mv, int& mi, int& mp) {
    bool take = (cand > mv) || ((cand == mv) && (m < mi));
    if (take) {
#pragma unroll
        for (int k = 0; k < 9; ++k) if (k == mp) { v[k] = cand; ix[k] = m; }
        float nv = v[0]; int ni = ix[0]; int np = 0;
#pragma unroll
        for (int k = 1; k < 9; ++k) {
            if (v[k] < nv || (v[k] == nv && ix[k] > ni)) { nv = v[k]; ni = ix[k]; np = k; }
        }
        mv = nv; mi = ni; mp = np;
    }
}

// ---------------- Kernel 2: fused sim + top-k (R9 structure FROZEN; iout now u16) ----------------
// 272us, absmax 0.0078, FETCH 16.2MB, MFMA busy ~43us ~= the 16x16-MFMA floor (~48us).
__global__ __launch_bounds__(256) void k_sim_topk(const f16* __restrict__ xh, const f16* __restrict__ xl,
                                                  float* __restrict__ vout, unsigned short* __restrict__ iout) {
    __shared__ f16x8          stg[2][32][16];  // 16KB staged 32-m window: [hl][row][frag^(row&7)]
    __shared__ float          sv[32][CAP + 1];
    __shared__ unsigned short si[32][CAP + 2];
    __shared__ int   cnt[32];
    __shared__ int   nbad;
    __shared__ int   badrows[32];

    const int id   = blockIdx.x;                  // 0..2047
    const int b    = (id & 7) + 8 * (id >> 9);
    const int r0   = ((id >> 3) & 63) * 32;
    const int t    = threadIdx.x;
    const int w    = t >> 6;
    const int lane = t & 63;
    const int jr   = lane & 15;
    const int q    = lane >> 4;
    const int tw   = w & 1;
    const int mh   = w >> 1;

    if (t < 32) cnt[t] = 0;
    if (t == 0) nbad = 0;

    f16x8 bh[4], bl[4];
    {
        int rr = b * NN + min(r0 + tw * 16 + jr, NN - 1);
        const f16* pH = xh + (size_t)rr * CC;
        const f16* pL = xl + (size_t)rr * CC;
#pragma unroll
        for (int s = 0; s < 4; ++s) {
            bh[s] = *(const f16x8*)(pH + s * 32 + q * 8);
            bl[s] = *(const f16x8*)(pL + s * 32 + q * 8);
        }
    }

    const int fi_ = t & 15;
    const int ri_ = t >> 4;
    const int fx  = fi_ ^ (ri_ & 7);
    const int rbuf = tw * 16 + jr;

    f16x8 h0r, h1r, l0r, l1r;
    {
        size_t g0 = (size_t)(b * NN + min(ri_, NN - 1)) * CC + fi_ * 8;
        size_t g1 = (size_t)(b * NN + min(ri_ + 16, NN - 1)) * CC + fi_ * 8;
        h0r = *(const f16x8*)(xh + g0);  h1r = *(const f16x8*)(xh + g1);
        l0r = *(const f16x8*)(xl + g0);  l1r = *(const f16x8*)(xl + g1);
    }

    for (int chunk = 0; chunk < 64; ++chunk) {
        __syncthreads();
        stg[0][ri_][fx]      = h0r;
        stg[0][ri_ + 16][fx] = h1r;
        stg[1][ri_][fx]      = l0r;
        stg[1][ri_ + 16][fx] = l1r;
        __syncthreads();
        if (chunk < 63) {
            size_t g0 = (size_t)(b * NN + min((chunk + 1) * 32 + ri_, NN - 1)) * CC + fi_ * 8;
            size_t g1 = (size_t)(b * NN + min((chunk + 1) * 32 + ri_ + 16, NN - 1)) * CC + fi_ * 8;
            h0r = *(const f16x8*)(xh + g0);  h1r = *(const f16x8*)(xh + g1);
            l0r = *(const f16x8*)(xl + g0);  l1r = *(const f16x8*)(xl + g1);
        }
        __builtin_amdgcn_sched_barrier(0);

        const int mb   = chunk * 32 + mh * 16;
        const int arow = mh * 16 + jr;
        const int axr  = arow & 7;
        f32x4 hh = {0.f, 0.f, 0.f, 0.f}, ll = {0.f, 0.f, 0.f, 0.f};
#pragma unroll
        for (int s = 0; s < 4; ++s) {
            f16x8 ah = stg[0][arow][(s * 4 + q) ^ axr];
            f16x8 al = stg[1][arow][(s * 4 + q) ^ axr];
            hh = __builtin_amdgcn_mfma_f32_16x16x32_f16(ah, bh[s], hh, 0, 0, 0);
            ll = __builtin_amdgcn_mfma_f32_16x16x32_f16(ah, bl[s], ll, 0, 0, 0);
            ll = __builtin_amdgcn_mfma_f32_16x16x32_f16(al, bh[s], ll, 0, 0, 0);
        }
#pragma unroll
        for (int reg = 0; reg < 4; ++reg) {
            int m = mb + q * 4 + reg;
            float c0 = hh[reg] * S28 + ll[reg] * S40;
            if (m < NN && c0 > T0F) {
                int pos = atomicAdd(&cnt[rbuf], 1);
                if (pos < CAP) { sv[rbuf][pos] = c0; si[rbuf][pos] = (unsigned short)m; }
            }
        }
    }
    __syncthreads();

    if (t < 32) {
        int r = r0 + t;
        if (r < NN) {
            int c = cnt[t];
            if (c >= 9 && c <= CAP) {
                float fv[9]; int fi[9];
#pragma unroll
                for (int k = 0; k < 9; ++k) { fv[k] = -3.0e38f; fi[k] = 0x7fffffff; }
                float mv = -3.0e38f; int mi = 0x7fffffff; int mp = 0;
                for (int j = 0; j < c; ++j) ins9(sv[t][j], (int)si[t][j], fv, fi, mv, mi, mp);
                float s = 1e-6f;
#pragma unroll
                for (int k = 0; k < 9; ++k) s += fv[k];
                float inv = 1.0f / s;
                int base = (b * NN + r) * KK;
#pragma unroll
                for (int k = 0; k < 9; ++k) { vout[base + k] = fv[k] * inv; iout[base + k] = (unsigned short)fi[k]; }
            } else {
                int slot = atomicAdd(&nbad, 1);
                badrows[slot] = r;
            }
        }
    }
    __syncthreads();

    if (w == 0) {
        int nb = nbad;
        for (int ib = 0; ib < nb; ++ib) {
            int r = badrows[ib];
            const f16* rH = xh + ((size_t)b * NN + r) * CC;
            const f16* rL = xl + ((size_t)b * NN + r) * CC;
            float fv[9]; int fi[9];
#pragma unroll
            for (int k = 0; k < 9; ++k) { fv[k] = -3.0e38f; fi[k] = 0x7fffffff; }
            float mv = -3.0e38f; int mi = 0x7fffffff; int mp = 0;
            for (int m = lane; m < NN; m += 64) {
                const f16* mH = xh + ((size_t)b * NN + m) * CC;
                const f16* mL = xl + ((size_t)b * NN + m) * CC;
                float a1 = 0.f, a2 = 0.f;
                for (int c2 = 0; c2 < CC; ++c2) {
                    float hr = (float)rH[c2], hm = (float)mH[c2];
                    float lr = (float)rL[c2], lm = (float)mL[c2];
                    a1 += hr * hm;
                    a2 += hr * lm + lr * hm;
                }
                ins9(a1 * S28 + a2 * S40, m, fv, fi, mv, mi, mp);
            }
#pragma unroll
            for (int off = 1; off < 64; off <<= 1) {
                float pv[9]; int pi[9];
#pragma unroll
                for (int k = 0; k < 9; ++k) { pv[k] = __shfl_xor(fv[k], off); pi[k] = __shfl_xor(fi[k], off); }
#pragma unroll
                for (int k = 0; k < 9; ++k) ins9(pv[k], pi[k], fv, fi, mv, mi, mp);
            }
            if (lane == 0) {
                float s = 1e-6f;
#pragma unroll
                for (int k = 0; k < 9; ++k) s += fv[k];
                float inv = 1.0f / s;
                int base = (b * NN + r) * KK;
#pragma unroll
                for (int k = 0; k < 9; ++k) { vout[base + k] = fv[k] * inv; iout[base + k] = (unsigned short)fi[k]; }
            }
        }
    }
}

// ---------------- Kernel 3pre: transpose + f16-split the weights: WT_h/WT_l in [j][c] ----------------
__global__ __launch_bounds__(256) void k_wsplit(const float* __restrict__ w1, const float* __restrict__ w2,
                                                f16* __restrict__ wth1, f16* __restrict__ wtl1,
                                                f16* __restrict__ wth2, f16* __restrict__ wtl2) {
    const float* w = blockIdx.x ? w2 : w1;
    f16* th = blockIdx.x ? wth2 : wth1;
    f16* tl = blockIdx.x ? wtl2 : wtl1;
    for (int e = threadIdx.x; e < CC * CC; e += 256) {
        int c = e >> 7, j = e & 127;
        float ws_ = w[e] * 16384.0f;               // coalesced read w[c][j]
        f16 h = (f16)ws_;
        f16 l = (f16)((ws_ - (float)h) * 4096.0f);
        th[j * CC + c] = h;                        // scattered 2B writes (tiny kernel)
        tl[j * CC + c] = l;
    }
}

// ---------------- Kernel 3: MFMA split GEMM  out[g][j] = sum_c A[g][c] W[c][j] ----------------
// R11: replaces the scalar-FMA LDS GEMMs (each ~2MB LDS reads/block => ~55us LDS-bound).
// A given as hi/lo f16 split; W as transposed hi/lo split (WT[j][c]).
// out = (Ah.Wh)*sH + (Ah.Wl + Al.Wh)*sL  — same structure as the sim kernel; dropped
// Al.Wl term ~2e-6. Layer1: sH=S28,sL=S40 (A-scale 2^-14/2^-26); layer2: S26/S38
// (activation split 2^-12/2^-24 from k_gnsilu_split).
__global__ __launch_bounds__(256) void k_gemm_mf(const f16* __restrict__ ah, const f16* __restrict__ al,
                                                 const f16* __restrict__ wth, const f16* __restrict__ wtl,
                                                 float sH, float sL, float* __restrict__ out) {
    const int t    = threadIdx.x;
    const int w    = t >> 6;
    const int lane = t & 63;
    const int jr   = lane & 15;
    const int q    = lane >> 4;
    const int row0 = blockIdx.x * 32;

    // B-frags: WT rows j = w*32 + ct*16 + jr (L2-resident, shared by all blocks)
    f16x8 wbh[2][4], wbl[2][4];
#pragma unroll
    for (int ct = 0; ct < 2; ++ct) {
        int j = w * 32 + ct * 16 + jr;
        const f16* pH = wth + (size_t)j * CC;
        const f16* pL = wtl + (size_t)j * CC;
#pragma unroll
        for (int s = 0; s < 4; ++s) {
            wbh[ct][s] = *(const f16x8*)(pH + s * 32 + q * 8);
            wbl[ct][s] = *(const f16x8*)(pL + s * 32 + q * 8);
        }
    }

#pragma unroll
    for (int rt = 0; rt < 2; ++rt) {
        int arow = row0 + rt * 16 + jr;
        const f16* pA  = ah + (size_t)arow * CC;
        const f16* pAl = al + (size_t)arow * CC;
        f16x8 af[4], alf[4];
#pragma unroll
        for (int s = 0; s < 4; ++s) {
            af[s]  = *(const f16x8*)(pA  + s * 32 + q * 8);
            alf[s] = *(const f16x8*)(pAl + s * 32 + q * 8);
        }
        f32x4 hh0 = {0.f,0.f,0.f,0.f}, ll0 = {0.f,0.f,0.f,0.f};
        f32x4 hh1 = {0.f,0.f,0.f,0.f}, ll1 = {0.f,0.f,0.f,0.f};
#pragma unroll
        for (int s = 0; s < 4; ++s) {
            hh0 = __builtin_amdgcn_mfma_f32_16x16x32_f16(af[s],  wbh[0][s], hh0, 0, 0, 0);
            ll0 = __builtin_amdgcn_mfma_f32_16x16x32_f16(af[s],  wbl[0][s], ll0, 0, 0, 0);
            ll0 = __builtin_amdgcn_mfma_f32_16x16x32_f16(alf[s], wbh[0][s], ll0, 0, 0, 0);
            hh1 = __builtin_amdgcn_mfma_f32_16x16x32_f16(af[s],  wbh[1][s], hh1, 0, 0, 0);
            ll1 = __builtin_amdgcn_mfma_f32_16x16x32_f16(af[s],  wbl[1][s], ll1, 0, 0, 0);
            ll1 = __builtin_amdgcn_mfma_f32_16x16x32_f16(alf[s], wbh[1][s], ll1, 0, 0, 0);
        }
        // D[m=q*4+reg][j=jr]: store both col-tiles
#pragma unroll
        for (int reg = 0; reg < 4; ++reg) {
            int orow = row0 + rt * 16 + q * 4 + reg;
            size_t ob = (size_t)orow * CC + w * 32 + jr;
            out[ob]      = hh0[reg] * sH + ll0[reg] * sL;
            out[ob + 16] = hh1[reg] * sH + ll1[reg] * sL;
        }
    }
}

// ---------------- Kernel 4: gather + weighted sum + bias (idx now u16) ----------------
__global__ __launch_bounds__(256) void k_gather(const float* __restrict__ xt,
                                                const float* __restrict__ v,
                                                const unsigned short* __restrict__ idx,
                                                const float* __restrict__ bias,
                                                float* __restrict__ out) {
    int t = threadIdx.x;
    int g = blockIdx.x * 2 + (t >> 7);
    int c = t & 127;
    if (g >= ROWS_TOTAL) return;
    int b = g / NN;
    int nb = b * NN;
    float acc = bias[c];
    int base = g * KK;
#pragma unroll
    for (int k = 0; k < KK; ++k) {
        int   ii = (int)idx[base + k];
        float vv = v[base + k];
        acc += vv * xt[(size_t)(nb + ii) * CC + c];
    }
    out[(size_t)g * CC + c] = acc;
}

// ---------------- Kernel 5: GroupNorm stats per (b, group) ----------------
__global__ __launch_bounds__(256) void k_gnstats(const float* __restrict__ xin,
                                                 float* __restrict__ stats) {
    int bg = blockIdx.x; int b = bg >> 2; int gg = bg & 3;
    size_t base = (size_t)b * (NN * CC) + gg * CPG;
    float s1 = 0.f, s2 = 0.f;
    for (int i = threadIdx.x; i < NN * CPG; i += 256) {
        float x = xin[base + (size_t)(i >> 5) * CC + (i & 31)];
        s1 += x; s2 += x * x;
    }
#pragma unroll
    for (int off = 32; off > 0; off >>= 1) { s1 += __shfl_xor(s1, off); s2 += __shfl_xor(s2, off); }
    __shared__ float r1[4], r2[4];
    int w = threadIdx.x >> 6;
    if ((threadIdx.x & 63) == 0) { r1[w] = s1; r2[w] = s2; }
    __syncthreads();
    if (threadIdx.x == 0) {
        float a = r1[0] + r1[1] + r1[2] + r1[3];
        float qq = r2[0] + r2[1] + r2[2] + r2[3];
        const float inv = 1.0f / (float)(NN * CPG);
        float mean = a * inv;
        float var = qq * inv - mean * mean;
        stats[bg * 2]     = mean;
        stats[bg * 2 + 1] = rsqrtf(fmaxf(var, 0.f) + GN_EPS);
    }
}

// ---------------- Kernel 6: GN apply + SiLU -> f16 split output (feeds layer-2 MFMA GEMM) ----------------
// Split scale 4096/4096: v = vh*2^-12 + vl*2^-24. |SiLU(y)| <~ 6 -> vh <= ~24576 < f16 max.
__global__ __launch_bounds__(256) void k_gnsilu_split(const float* __restrict__ xin,
                                                      const float* __restrict__ stats,
                                                      const float* __restrict__ gamma,
                                                      const float* __restrict__ beta,
                                                      f16* __restrict__ vh, f16* __restrict__ vl) {
    size_t e4 = ((size_t)blockIdx.x * 256 + threadIdx.x) * 4;
    int c0 = (int)(e4 & 127);
    int b  = (int)(e4 / (NN * CC));
    int gg = c0 >> 5;
    float mean = stats[(b * 4 + gg) * 2];
    float rstd = stats[(b * 4 + gg) * 2 + 1];
    float4 x = *(const float4*)&xin[e4];
    float g0 = gamma[c0], g1 = gamma[c0 + 1], g2 = gamma[c0 + 2], g3 = gamma[c0 + 3];
    float p0 = beta[c0],  p1 = beta[c0 + 1],  p2 = beta[c0 + 2],  p3 = beta[c0 + 3];
    float y0 = (x.x - mean) * rstd * g0 + p0;
    float y1 = (x.y - mean) * rstd * g1 + p1;
    float y2 = (x.z - mean) * rstd * g2 + p2;
    float y3 = (x.w - mean) * rstd * g3 + p3;
    float r0 = y0 / (1.0f + expf(-y0));
    float r1 = y1 / (1.0f + expf(-y1));
    float r2 = y2 / (1.0f + expf(-y2));
    float r3 = y3 / (1.0f + expf(-y3));
    f16x4 hv, lv;
    float s0 = r0 * 4096.0f; hv[0] = (f16)s0; lv[0] = (f16)((s0 - (float)hv[0]) * 4096.0f);
    float s1 = r1 * 4096.0f; hv[1] = (f16)s1; lv[1] = (f16)((s1 - (float)hv[1]) * 4096.0f);
    float s2 = r2 * 4096.0f; hv[2] = (f16)s2; lv[2] = (f16)((s2 - (float)hv[2]) * 4096.0f);
    float s3 = r3 * 4096.0f; hv[3] = (f16)s3; lv[3] = (f16)((s3 - (float)hv[3]) * 4096.0f);
    *(f16x4*)&vh[e4] = hv;
    *(f16x4*)&vl[e4] = lv;
}

// ---------------- Kernel 7: GN apply + SiLU + transpose to [B][C][N], fp32 out ----------------
__global__ __launch_bounds__(256) void k_gnsilu_out(const float* __restrict__ xin,
                                                    const float* __restrict__ stats,
                                                    const float* __restrict__ gamma,
                                                    const float* __restrict__ beta,
                                                    float* __restrict__ out) {
    __shared__ float tile[32 * 65];
    int b = blockIdx.z, ct = blockIdx.y, nt = blockIdx.x;
    int c0 = ct * 32, n0 = nt * 64;
    int t = threadIdx.x;
    int cj = t & 31, ni0 = t >> 5;
    int gg = c0 >> 5;
    float mean = stats[(b * 4 + gg) * 2];
    float rstd = stats[(b * 4 + gg) * 2 + 1];
    float gm = gamma[c0 + cj];
    float bt = beta[c0 + cj];
#pragma unroll
    for (int i = 0; i < 8; ++i) {
        int n = n0 + ni0 + i * 8;
        if (n < NN) {
            float x = xin[((size_t)b * NN + n) * CC + c0 + cj];
            float y = (x - mean) * rstd * gm + bt;
            y = y / (1.0f + expf(-y));
            tile[cj * 65 + ni0 + i * 8] = y;
        }
    }
    __syncthreads();
    int nj = t & 63, ci0 = t >> 6;
#pragma unroll
    for (int i = 0; i < 8; ++i) {
        int c = ci0 + i * 4;
        int n = n0 + nj;
        if (n < NN) out[((size_t)b * CC + c0 + c) * NN + n] = tile[c * 65 + nj];
    }
}

extern "C" void kernel_launch(void* const* d_in, const int* in_sizes, int n_in,
                              void* d_out, int out_size, void* d_ws, size_t ws_size,
                              hipStream_t stream) {
    const float* x      = (const float*)d_in[0];
    const float* w1     = (const float*)d_in[1];
    const float* b1     = (const float*)d_in[2];
    const float* w2     = (const float*)d_in[3];
    const float* b2     = (const float*)d_in[4];
    const float* gamma1 = (const float*)d_in[5];
    const float* beta1  = (const float*)d_in[6];
    const float* gamma2 = (const float*)d_in[7];
    const float* beta2  = (const float*)d_in[8];
    float* out = (float*)d_out;

    const size_t BIG = (size_t)ROWS_TOTAL * CC;   // 8,294,400
    const size_t RK  = (size_t)ROWS_TOTAL * KK;   // 583,200
    float* ws   = (float*)d_ws;
    // Layout (floats): [bufB: BIG][xh/xl|bufA: BIG][vbuf: RK][ibuf16: RK/2][wt: 32768][stats: 256]
    // Total = 17,496,624 floats < previous footprint 17,755,456 (ibuf int->u16 freed the wt space).
    float* bufB = ws;
    f16*   xh   = (f16*)(ws + BIG);
    f16*   xl   = xh + BIG;
    float* bufA = ws + BIG;                        // ALIASES xh/xl; first written by gather1
    float* vbuf = ws + 2 * BIG;
    unsigned short* ibuf = (unsigned short*)(ws + 2 * BIG + RK);
    f16*   wth1 = (f16*)(ws + 2 * BIG + RK + RK / 2);
    f16*   wtl1 = wth1 + CC * CC;
    f16*   wth2 = wtl1 + CC * CC;
    f16*   wtl2 = wth2 + CC * CC;
    float* stats = ws + 2 * BIG + RK + RK / 2 + 2 * CC * CC;  // 4*CC*CC f16 = 2*CC*CC floats
    // layer-2 activations split: reuse bufB region (BIG floats = 2*BIG f16)
    f16*   vh = (f16*)bufB;
    f16*   vl = vh + BIG;

    k_normalize<<<dim3(32, BN), 256, 0, stream>>>(x, xh, xl);
    k_wsplit<<<2, 256, 0, stream>>>(w1, w2, wth1, wtl1, wth2, wtl2);
    k_sim_topk<<<2048, 256, 0, stream>>>(xh, xl, vbuf, ibuf);

    // layer 1 (xh/xl last read by gemm1; bufA aliases them and is written by gather1 after)
    k_gemm_mf<<<ROWS_TOTAL / 32, 256, 0, stream>>>(xh, xl, wth1, wtl1, S28, S40, bufB);
    k_gather<<<ROWS_TOTAL / 2, 256, 0, stream>>>(bufB, vbuf, ibuf, b1, bufA);
    k_gnstats<<<BN * NGROUP, 256, 0, stream>>>(bufA, stats);
    k_gnsilu_split<<<(int)(BIG / 1024), 256, 0, stream>>>(bufA, stats, gamma1, beta1, vh, vl);

    // layer 2 (vh/vl in bufB region, consumed by gemm2 before gather2 overwrites bufB)
    k_gemm_mf<<<ROWS_TOTAL / 32, 256, 0, stream>>>(vh, vl, wth2, wtl2, S26, S38, bufA);
    k_gather<<<ROWS_TOTAL / 2, 256, 0, stream>>>(bufA, vbuf, ibuf, b2, bufB);
    k_gnstats<<<BN * NGROUP, 256, 0, stream>>>(bufB, stats);
    k_gnsilu_out<<<dim3((NN + 63) / 64, NGROUP, BN), 256, 0, stream>>>(bufB, stats, gamma2, beta2, out);
}

// Round 12
// 629.844 us; speedup vs baseline: 1.0663x; 1.0663x over previous
//
#include <hip/hip_runtime.h>
#include <hip/hip_bf16.h>

#define BN 32
#define CC 128
#define NN 2025
#define KK 9
#define NGROUP 4
#define CPG 32
#define GN_EPS 1e-5f
#define ROWS_TOTAL (BN * NN)   // 64800

typedef _Float16 f16;
typedef __attribute__((ext_vector_type(8))) _Float16 f16x8;
typedef __attribute__((ext_vector_type(4))) float f32x4;

#define S28 3.725290298461914e-09f   // 2^-28  (xh*wh)
#define S40 9.094947017729282e-13f   // 2^-40  (xh*wl + xl*wh)
#define S26 1.4901161193847656e-08f  // 2^-26  (vh*wh, layer2)
#define S38 3.637978807091713e-12f   // 2^-38  (vh*wl + vl*wh, layer2)

#define T0F 0.17f                    // survivor threshold (9th-best ~0.23, min ~0.19)
#define CAP 100                      // per-row survivor capacity (mean ~55, max ~95; overflow -> exact fallback)

// ---------------- Kernel 1: L2 normalize -> scaled f16 split (R10 transpose version) ----------------
__global__ __launch_bounds__(256) void k_normalize(const float* __restrict__ x,
                                                   f16* __restrict__ xh, f16* __restrict__ xl) {
    __shared__ float tile[128][65];
    const int b  = blockIdx.y;
    const int n0 = blockIdx.x * 64;
    const int t  = threadIdx.x;
    const int w  = t >> 6;
    const int lane = t & 63;
    const int gn_ld = min(n0 + lane, NN - 1);   // tail clamp (dup value, never stored)

    for (int it = 0; it < 32; ++it) {
        int c = it * 4 + w;
        tile[c][lane] = x[((size_t)(b * CC + c)) * NN + gn_ld];
    }
    __syncthreads();

    for (int i = 0; i < 16; ++i) {
        int n  = w * 16 + i;
        int gn = n0 + n;
        if (gn < NN) {
            float v0 = tile[lane][n];
            float v1 = tile[lane + 64][n];
            float ss = v0 * v0 + v1 * v1;
#pragma unroll
            for (int off = 32; off > 0; off >>= 1) ss += __shfl_xor(ss, off);
            float s = 1.0f / fmaxf(sqrtf(ss), 1e-12f);
            v0 *= s; v1 *= s;
            float w0 = v0 * 16384.0f, w1 = v1 * 16384.0f;
            f16 h0 = (f16)w0, h1 = (f16)w1;
            f16 l0 = (f16)((w0 - (float)h0) * 4096.0f);
            f16 l1 = (f16)((w1 - (float)h1) * 4096.0f);
            size_t base = (size_t)(b * NN + gn) * CC;
            xh[base + lane] = h0;  xh[base + lane + 64] = h1;
            xl[base + lane] = l0;  xl[base + lane + 64] = l1;
        }
    }
}

// top-9 insert: (value desc, index asc) ordering; order-independent tie rules — EXACT
__device__ __forceinline__ void ins9(float cand, int m, float* v, int* ix,
                                     float& mv, int& mi, int& mp) {
    bool take = (cand > mv) || ((cand == mv) && (m < mi));
    if (take) {
#pragma unroll
        for (int k = 0; k < 9; ++k) if (k == mp) { v[k] = cand; ix[k] = m; }
        float nv = v[0]; int ni = ix[0]; int np = 0;
#pragma unroll
        for (int k = 1; k < 9; ++k) {
            if (v[k] < nv || (v[k] == nv && ix[k] > ni)) { nv = v[k]; ni = ix[k]; np = k; }
        }
        mv = nv; mi = ni; mp = np;
    }
}

// ---------------- Kernel 2: fused sim + top-k (R9 structure FROZEN) ----------------
__global__ __launch_bounds__(256) void k_sim_topk(const f16* __restrict__ xh, const f16* __restrict__ xl,
                                                  float* __restrict__ vout, unsigned short* __restrict__ iout) {
    __shared__ f16x8          stg[2][32][16];  // 16KB staged 32-m window: [hl][row][frag^(row&7)]
    __shared__ float          sv[32][CAP + 1];
    __shared__ unsigned short si[32][CAP + 2];
    __shared__ int   cnt[32];
    __shared__ int   nbad;
    __shared__ int   badrows[32];

    const int id   = blockIdx.x;                  // 0..2047
    const int b    = (id & 7) + 8 * (id >> 9);
    const int r0   = ((id >> 3) & 63) * 32;
    const int t    = threadIdx.x;
    const int w    = t >> 6;
    const int lane = t & 63;
    const int jr   = lane & 15;
    const int q    = lane >> 4;
    const int tw   = w & 1;
    const int mh   = w >> 1;

    if (t < 32) cnt[t] = 0;
    if (t == 0) nbad = 0;

    f16x8 bh[4], bl[4];
    {
        int rr = b * NN + min(r0 + tw * 16 + jr, NN - 1);
        const f16* pH = xh + (size_t)rr * CC;
        const f16* pL = xl + (size_t)rr * CC;
#pragma unroll
        for (int s = 0; s < 4; ++s) {
            bh[s] = *(const f16x8*)(pH + s * 32 + q * 8);
            bl[s] = *(const f16x8*)(pL + s * 32 + q * 8);
        }
    }

    const int fi_ = t & 15;
    const int ri_ = t >> 4;
    const int fx  = fi_ ^ (ri_ & 7);
    const int rbuf = tw * 16 + jr;

    f16x8 h0r, h1r, l0r, l1r;
    {
        size_t g0 = (size_t)(b * NN + min(ri_, NN - 1)) * CC + fi_ * 8;
        size_t g1 = (size_t)(b * NN + min(ri_ + 16, NN - 1)) * CC + fi_ * 8;
        h0r = *(const f16x8*)(xh + g0);  h1r = *(const f16x8*)(xh + g1);
        l0r = *(const f16x8*)(xl + g0);  l1r = *(const f16x8*)(xl + g1);
    }

    for (int chunk = 0; chunk < 64; ++chunk) {
        __syncthreads();
        stg[0][ri_][fx]      = h0r;
        stg[0][ri_ + 16][fx] = h1r;
        stg[1][ri_][fx]      = l0r;
        stg[1][ri_ + 16][fx] = l1r;
        __syncthreads();
        if (chunk < 63) {
            size_t g0 = (size_t)(b * NN + min((chunk + 1) * 32 + ri_, NN - 1)) * CC + fi_ * 8;
            size_t g1 = (size_t)(b * NN + min((chunk + 1) * 32 + ri_ + 16, NN - 1)) * CC + fi_ * 8;
            h0r = *(const f16x8*)(xh + g0);  h1r = *(const f16x8*)(xh + g1);
            l0r = *(const f16x8*)(xl + g0);  l1r = *(const f16x8*)(xl + g1);
        }
        __builtin_amdgcn_sched_barrier(0);

        const int mb   = chunk * 32 + mh * 16;
        const int arow = mh * 16 + jr;
        const int axr  = arow & 7;
        f32x4 hh = {0.f, 0.f, 0.f, 0.f}, ll = {0.f, 0.f, 0.f, 0.f};
#pragma unroll
        for (int s = 0; s < 4; ++s) {
            f16x8 ah = stg[0][arow][(s * 4 + q) ^ axr];
            f16x8 al = stg[1][arow][(s * 4 + q) ^ axr];
            hh = __builtin_amdgcn_mfma_f32_16x16x32_f16(ah, bh[s], hh, 0, 0, 0);
            ll = __builtin_amdgcn_mfma_f32_16x16x32_f16(ah, bl[s], ll, 0, 0, 0);
            ll = __builtin_amdgcn_mfma_f32_16x16x32_f16(al, bh[s], ll, 0, 0, 0);
        }
#pragma unroll
        for (int reg = 0; reg < 4; ++reg) {
            int m = mb + q * 4 + reg;
            float c0 = hh[reg] * S28 + ll[reg] * S40;
            if (m < NN && c0 > T0F) {
                int pos = atomicAdd(&cnt[rbuf], 1);
                if (pos < CAP) { sv[rbuf][pos] = c0; si[rbuf][pos] = (unsigned short)m; }
            }
        }
    }
    __syncthreads();

    if (t < 32) {
        int r = r0 + t;
        if (r < NN) {
            int c = cnt[t];
            if (c >= 9 && c <= CAP) {
                float fv[9]; int fi[9];
#pragma unroll
                for (int k = 0; k < 9; ++k) { fv[k] = -3.0e38f; fi[k] = 0x7fffffff; }
                float mv = -3.0e38f; int mi = 0x7fffffff; int mp = 0;
                for (int j = 0; j < c; ++j) ins9(sv[t][j], (int)si[t][j], fv, fi, mv, mi, mp);
                float s = 1e-6f;
#pragma unroll
                for (int k = 0; k < 9; ++k) s += fv[k];
                float inv = 1.0f / s;
                int base = (b * NN + r) * KK;
#pragma unroll
                for (int k = 0; k < 9; ++k) { vout[base + k] = fv[k] * inv; iout[base + k] = (unsigned short)fi[k]; }
            } else {
                int slot = atomicAdd(&nbad, 1);
                badrows[slot] = r;
            }
        }
    }
    __syncthreads();

    if (w == 0) {
        int nb = nbad;
        for (int ib = 0; ib < nb; ++ib) {
            int r = badrows[ib];
            const f16* rH = xh + ((size_t)b * NN + r) * CC;
            const f16* rL = xl + ((size_t)b * NN + r) * CC;
            float fv[9]; int fi[9];
#pragma unroll
            for (int k = 0; k < 9; ++k) { fv[k] = -3.0e38f; fi[k] = 0x7fffffff; }
            float mv = -3.0e38f; int mi = 0x7fffffff; int mp = 0;
            for (int m = lane; m < NN; m += 64) {
                const f16* mH = xh + ((size_t)b * NN + m) * CC;
                const f16* mL = xl + ((size_t)b * NN + m) * CC;
                float a1 = 0.f, a2 = 0.f;
                for (int c2 = 0; c2 < CC; ++c2) {
                    float hr = (float)rH[c2], hm = (float)mH[c2];
                    float lr = (float)rL[c2], lm = (float)mL[c2];
                    a1 += hr * hm;
                    a2 += hr * lm + lr * hm;
                }
                ins9(a1 * S28 + a2 * S40, m, fv, fi, mv, mi, mp);
            }
#pragma unroll
            for (int off = 1; off < 64; off <<= 1) {
                float pv[9]; int pi[9];
#pragma unroll
                for (int k = 0; k < 9; ++k) { pv[k] = __shfl_xor(fv[k], off); pi[k] = __shfl_xor(fi[k], off); }
#pragma unroll
                for (int k = 0; k < 9; ++k) ins9(pv[k], pi[k], fv, fi, mv, mi, mp);
            }
            if (lane == 0) {
                float s = 1e-6f;
#pragma unroll
                for (int k = 0; k < 9; ++k) s += fv[k];
                float inv = 1.0f / s;
                int base = (b * NN + r) * KK;
#pragma unroll
                for (int k = 0; k < 9; ++k) { vout[base + k] = fv[k] * inv; iout[base + k] = (unsigned short)fi[k]; }
            }
        }
    }
}

// ---------------- Kernel 3pre: transpose + f16-split the weights: WT_h/WT_l in [j][c] ----------------
__global__ __launch_bounds__(256) void k_wsplit(const float* __restrict__ w1, const float* __restrict__ w2,
                                                f16* __restrict__ wth1, f16* __restrict__ wtl1,
                                                f16* __restrict__ wth2, f16* __restrict__ wtl2) {
    const float* w = blockIdx.x ? w2 : w1;
    f16* th = blockIdx.x ? wth2 : wth1;
    f16* tl = blockIdx.x ? wtl2 : wtl1;
    for (int e = threadIdx.x; e < CC * CC; e += 256) {
        int c = e >> 7, j = e & 127;
        float ws_ = w[e] * 16384.0f;
        f16 h = (f16)ws_;
        f16 l = (f16)((ws_ - (float)h) * 4096.0f);
        th[j * CC + c] = h;
        tl[j * CC + c] = l;
    }
}

// ---------------- Kernel 3: tiled MFMA split GEMM, 128 rows/block, LDS-staged A ----------------
// R12: R11's k_gemm_mf re-committed the R7 sin — 4 waves loading the SAME A rows from
// global (4x scattered traffic) + W-frags rescattered per 32-row block (130MB). Fix with
// the proven sim_topk staging skeleton: A staged coalesced once per block (4 chunks of
// 32 rows), all waves ds_read; W-frags in regs once per block, amortized over 128 rows
// (W traffic 130->32MB). MFMA expression/scales identical to R11 (numerics unchanged).
__global__ __launch_bounds__(256) void k_gemm_tile(const f16* __restrict__ ah, const f16* __restrict__ al,
                                                   const f16* __restrict__ wth, const f16* __restrict__ wtl,
                                                   float sH, float sL, float* __restrict__ out) {
    __shared__ f16x8 stg[2][32][16];   // [hl][row][frag^(row&7)] — sim_topk layout
    const int t    = threadIdx.x;
    const int w    = t >> 6;
    const int lane = t & 63;
    const int jr   = lane & 15;
    const int q    = lane >> 4;
    const int row0 = blockIdx.x * 128;

    // W-frags once per block: wave w owns j = w*32 + ct*16 + jr
    f16x8 wbh[2][4], wbl[2][4];
#pragma unroll
    for (int ct = 0; ct < 2; ++ct) {
        int j = w * 32 + ct * 16 + jr;
        const f16* pH = wth + (size_t)j * CC;
        const f16* pL = wtl + (size_t)j * CC;
#pragma unroll
        for (int s = 0; s < 4; ++s) {
            wbh[ct][s] = *(const f16x8*)(pH + s * 32 + q * 8);
            wbl[ct][s] = *(const f16x8*)(pL + s * 32 + q * 8);
        }
    }

    const int fi_ = t & 15;
    const int ri_ = t >> 4;
    const int fx  = fi_ ^ (ri_ & 7);

    // preload chunk 0 (rows row0+ri_, row0+ri_+16; clamped)
    f16x8 h0r, h1r, l0r, l1r;
    {
        size_t g0 = (size_t)min(row0 + ri_, ROWS_TOTAL - 1) * CC + fi_ * 8;
        size_t g1 = (size_t)min(row0 + ri_ + 16, ROWS_TOTAL - 1) * CC + fi_ * 8;
        h0r = *(const f16x8*)(ah + g0);  h1r = *(const f16x8*)(ah + g1);
        l0r = *(const f16x8*)(al + g0);  l1r = *(const f16x8*)(al + g1);
    }

    for (int chunk = 0; chunk < 4; ++chunk) {
        __syncthreads();
        stg[0][ri_][fx]      = h0r;
        stg[0][ri_ + 16][fx] = h1r;
        stg[1][ri_][fx]      = l0r;
        stg[1][ri_ + 16][fx] = l1r;
        __syncthreads();
        if (chunk < 3) {
            size_t g0 = (size_t)min(row0 + (chunk + 1) * 32 + ri_, ROWS_TOTAL - 1) * CC + fi_ * 8;
            size_t g1 = (size_t)min(row0 + (chunk + 1) * 32 + ri_ + 16, ROWS_TOTAL - 1) * CC + fi_ * 8;
            h0r = *(const f16x8*)(ah + g0);  h1r = *(const f16x8*)(ah + g1);
            l0r = *(const f16x8*)(al + g0);  l1r = *(const f16x8*)(al + g1);
        }
        __builtin_amdgcn_sched_barrier(0);

#pragma unroll
        for (int rt = 0; rt < 2; ++rt) {
            const int arow = rt * 16 + jr;
            const int axr  = arow & 7;
            f16x8 af[4], alf[4];
#pragma unroll
            for (int s = 0; s < 4; ++s) {
                af[s]  = stg[0][arow][(s * 4 + q) ^ axr];
                alf[s] = stg[1][arow][(s * 4 + q) ^ axr];
            }
            f32x4 hh0 = {0.f,0.f,0.f,0.f}, ll0 = {0.f,0.f,0.f,0.f};
            f32x4 hh1 = {0.f,0.f,0.f,0.f}, ll1 = {0.f,0.f,0.f,0.f};
#pragma unroll
            for (int s = 0; s < 4; ++s) {
                hh0 = __builtin_amdgcn_mfma_f32_16x16x32_f16(af[s],  wbh[0][s], hh0, 0, 0, 0);
                ll0 = __builtin_amdgcn_mfma_f32_16x16x32_f16(af[s],  wbl[0][s], ll0, 0, 0, 0);
                ll0 = __builtin_amdgcn_mfma_f32_16x16x32_f16(alf[s], wbh[0][s], ll0, 0, 0, 0);
                hh1 = __builtin_amdgcn_mfma_f32_16x16x32_f16(af[s],  wbh[1][s], hh1, 0, 0, 0);
                ll1 = __builtin_amdgcn_mfma_f32_16x16x32_f16(af[s],  wbl[1][s], ll1, 0, 0, 0);
                ll1 = __builtin_amdgcn_mfma_f32_16x16x32_f16(alf[s], wbh[1][s], ll1, 0, 0, 0);
            }
#pragma unroll
            for (int reg = 0; reg < 4; ++reg) {
                int orow = row0 + chunk * 32 + rt * 16 + q * 4 + reg;
                if (orow < ROWS_TOTAL) {
                    size_t ob = (size_t)orow * CC + w * 32 + jr;
                    out[ob]      = hh0[reg] * sH + ll0[reg] * sL;
                    out[ob + 16] = hh1[reg] * sH + ll1[reg] * sL;
                }
            }
        }
    }
}

// ---------------- Kernel 3b: same tiled GEMM, but A-staging applies GN+SiLU + f16-split ----------------
// Fuses the former k_gnsilu_split INTO the layer-2 GEMM's staging path (saves a full
// 33MB R + 33MB W pass + one launch). Expression sequence identical to R11's
// k_gnsilu_split => staged values bit-identical => absmax unchanged.
__global__ __launch_bounds__(256) void k_gemm_tile_gn(const float* __restrict__ act,
                                                      const float* __restrict__ stats,
                                                      const float* __restrict__ gamma,
                                                      const float* __restrict__ beta,
                                                      const f16* __restrict__ wth, const f16* __restrict__ wtl,
                                                      float sH, float sL, float* __restrict__ out) {
    __shared__ f16x8 stg[2][32][16];
    const int t    = threadIdx.x;
    const int w    = t >> 6;
    const int lane = t & 63;
    const int jr   = lane & 15;
    const int q    = lane >> 4;
    const int row0 = blockIdx.x * 128;

    f16x8 wbh[2][4], wbl[2][4];
#pragma unroll
    for (int ct = 0; ct < 2; ++ct) {
        int j = w * 32 + ct * 16 + jr;
        const f16* pH = wth + (size_t)j * CC;
        const f16* pL = wtl + (size_t)j * CC;
#pragma unroll
        for (int s = 0; s < 4; ++s) {
            wbh[ct][s] = *(const f16x8*)(pH + s * 32 + q * 8);
            wbl[ct][s] = *(const f16x8*)(pL + s * 32 + q * 8);
        }
    }

    const int fi_ = t & 15;
    const int ri_ = t >> 4;
    const int fx  = fi_ ^ (ri_ & 7);
    const int gg  = fi_ >> 2;          // group of this thread's 8-column slice (c = fi_*8..+8)

    // per-thread gamma/beta slice (constant over the whole block)
    float gma[8], bta[8];
#pragma unroll
    for (int e = 0; e < 8; ++e) { gma[e] = gamma[fi_ * 8 + e]; bta[e] = beta[fi_ * 8 + e]; }

    // preload chunk 0 rows (fp32 activations)
    float4 pa0, pa1, pb0, pb1;
    int ra = min(row0 + ri_, ROWS_TOTAL - 1);
    int rb = min(row0 + ri_ + 16, ROWS_TOTAL - 1);
    {
        const float* p0 = act + (size_t)ra * CC + fi_ * 8;
        const float* p1 = act + (size_t)rb * CC + fi_ * 8;
        pa0 = *(const float4*)p0;  pa1 = *(const float4*)(p0 + 4);
        pb0 = *(const float4*)p1;  pb1 = *(const float4*)(p1 + 4);
    }

    for (int chunk = 0; chunk < 4; ++chunk) {
        __syncthreads();
        // GN + SiLU + 4096/4096 split (identical expressions to R11 k_gnsilu_split)
        {
            float va[8] = {pa0.x, pa0.y, pa0.z, pa0.w, pa1.x, pa1.y, pa1.z, pa1.w};
            float vb[8] = {pb0.x, pb0.y, pb0.z, pb0.w, pb1.x, pb1.y, pb1.z, pb1.w};
            int ba = ra / NN, bb = rb / NN;
            float ma = stats[(ba * 4 + gg) * 2], rsa = stats[(ba * 4 + gg) * 2 + 1];
            float mb = stats[(bb * 4 + gg) * 2], rsb = stats[(bb * 4 + gg) * 2 + 1];
            f16x8 hva, lva, hvb, lvb;
#pragma unroll
            for (int e = 0; e < 8; ++e) {
                float ya = (va[e] - ma) * rsa * gma[e] + bta[e];
                float ra_ = ya / (1.0f + expf(-ya));
                float sa = ra_ * 4096.0f;
                f16 h = (f16)sa; hva[e] = h; lva[e] = (f16)((sa - (float)h) * 4096.0f);
                float yb = (vb[e] - mb) * rsb * gma[e] + bta[e];
                float rb_ = yb / (1.0f + expf(-yb));
                float sb = rb_ * 4096.0f;
                f16 h2 = (f16)sb; hvb[e] = h2; lvb[e] = (f16)((sb - (float)h2) * 4096.0f);
            }
            stg[0][ri_][fx]      = hva;
            stg[0][ri_ + 16][fx] = hvb;
            stg[1][ri_][fx]      = lva;
            stg[1][ri_ + 16][fx] = lvb;
        }
        __syncthreads();
        if (chunk < 3) {
            ra = min(row0 + (chunk + 1) * 32 + ri_, ROWS_TOTAL - 1);
            rb = min(row0 + (chunk + 1) * 32 + ri_ + 16, ROWS_TOTAL - 1);
            const float* p0 = act + (size_t)ra * CC + fi_ * 8;
            const float* p1 = act + (size_t)rb * CC + fi_ * 8;
            pa0 = *(const float4*)p0;  pa1 = *(const float4*)(p0 + 4);
            pb0 = *(const float4*)p1;  pb1 = *(const float4*)(p1 + 4);
        }
        __builtin_amdgcn_sched_barrier(0);

#pragma unroll
        for (int rt = 0; rt < 2; ++rt) {
            const int arow = rt * 16 + jr;
            const int axr  = arow & 7;
            f16x8 af[4], alf[4];
#pragma unroll
            for (int s = 0; s < 4; ++s) {
                af[s]  = stg[0][arow][(s * 4 + q) ^ axr];
                alf[s] = stg[1][arow][(s * 4 + q) ^ axr];
            }
            f32x4 hh0 = {0.f,0.f,0.f,0.f}, ll0 = {0.f,0.f,0.f,0.f};
            f32x4 hh1 = {0.f,0.f,0.f,0.f}, ll1 = {0.f,0.f,0.f,0.f};
#pragma unroll
            for (int s = 0; s < 4; ++s) {
                hh0 = __builtin_amdgcn_mfma_f32_16x16x32_f16(af[s],  wbh[0][s], hh0, 0, 0, 0);
                ll0 = __builtin_amdgcn_mfma_f32_16x16x32_f16(af[s],  wbl[0][s], ll0, 0, 0, 0);
                ll0 = __builtin_amdgcn_mfma_f32_16x16x32_f16(alf[s], wbh[0][s], ll0, 0, 0, 0);
                hh1 = __builtin_amdgcn_mfma_f32_16x16x32_f16(af[s],  wbh[1][s], hh1, 0, 0, 0);
                ll1 = __builtin_amdgcn_mfma_f32_16x16x32_f16(af[s],  wbl[1][s], ll1, 0, 0, 0);
                ll1 = __builtin_amdgcn_mfma_f32_16x16x32_f16(alf[s], wbh[1][s], ll1, 0, 0, 0);
            }
#pragma unroll
            for (int reg = 0; reg < 4; ++reg) {
                int orow = row0 + chunk * 32 + rt * 16 + q * 4 + reg;
                if (orow < ROWS_TOTAL) {
                    size_t ob = (size_t)orow * CC + w * 32 + jr;
                    out[ob]      = hh0[reg] * sH + ll0[reg] * sL;
                    out[ob + 16] = hh1[reg] * sH + ll1[reg] * sL;
                }
            }
        }
    }
}

// ---------------- Kernel 4: gather + weighted sum + bias (idx u16) ----------------
__global__ __launch_bounds__(256) void k_gather(const float* __restrict__ xt,
                                                const float* __restrict__ v,
                                                const unsigned short* __restrict__ idx,
                                                const float* __restrict__ bias,
                                                float* __restrict__ out) {
    int t = threadIdx.x;
    int g = blockIdx.x * 2 + (t >> 7);
    int c = t & 127;
    if (g >= ROWS_TOTAL) return;
    int b = g / NN;
    int nb = b * NN;
    float acc = bias[c];
    int base = g * KK;
#pragma unroll
    for (int k = 0; k < KK; ++k) {
        int   ii = (int)idx[base + k];
        float vv = v[base + k];
        acc += vv * xt[(size_t)(nb + ii) * CC + c];
    }
    out[(size_t)g * CC + c] = acc;
}

// ---------------- Kernel 5: GroupNorm stats per (b, group) ----------------
__global__ __launch_bounds__(256) void k_gnstats(const float* __restrict__ xin,
                                                 float* __restrict__ stats) {
    int bg = blockIdx.x; int b = bg >> 2; int gg = bg & 3;
    size_t base = (size_t)b * (NN * CC) + gg * CPG;
    float s1 = 0.f, s2 = 0.f;
    for (int i = threadIdx.x; i < NN * CPG; i += 256) {
        float x = xin[base + (size_t)(i >> 5) * CC + (i & 31)];
        s1 += x; s2 += x * x;
    }
#pragma unroll
    for (int off = 32; off > 0; off >>= 1) { s1 += __shfl_xor(s1, off); s2 += __shfl_xor(s2, off); }
    __shared__ float r1[4], r2[4];
    int w = threadIdx.x >> 6;
    if ((threadIdx.x & 63) == 0) { r1[w] = s1; r2[w] = s2; }
    __syncthreads();
    if (threadIdx.x == 0) {
        float a = r1[0] + r1[1] + r1[2] + r1[3];
        float qq = r2[0] + r2[1] + r2[2] + r2[3];
        const float inv = 1.0f / (float)(NN * CPG);
        float mean = a * inv;
        float var = qq * inv - mean * mean;
        stats[bg * 2]     = mean;
        stats[bg * 2 + 1] = rsqrtf(fmaxf(var, 0.f) + GN_EPS);
    }
}

// ---------------- Kernel 7: GN apply + SiLU + transpose to [B][C][N], fp32 out ----------------
__global__ __launch_bounds__(256) void k_gnsilu_out(const float* __restrict__ xin,
                                                    const float* __restrict__ stats,
                                                    const float* __restrict__ gamma,
                                                    const float* __restrict__ beta,
                                                    float* __restrict__ out) {
    __shared__ float tile[32 * 65];
    int b = blockIdx.z, ct = blockIdx.y, nt = blockIdx.x;
    int c0 = ct * 32, n0 = nt * 64;
    int t = threadIdx.x;
    int cj = t & 31, ni0 = t >> 5;
    int gg = c0 >> 5;
    float mean = stats[(b * 4 + gg) * 2];
    float rstd = stats[(b * 4 + gg) * 2 + 1];
    float gm = gamma[c0 + cj];
    float bt = beta[c0 + cj];
#pragma unroll
    for (int i = 0; i < 8; ++i) {
        int n = n0 + ni0 + i * 8;
        if (n < NN) {
            float x = xin[((size_t)b * NN + n) * CC + c0 + cj];
            float y = (x - mean) * rstd * gm + bt;
            y = y / (1.0f + expf(-y));
            tile[cj * 65 + ni0 + i * 8] = y;
        }
    }
    __syncthreads();
    int nj = t & 63, ci0 = t >> 6;
#pragma unroll
    for (int i = 0; i < 8; ++i) {
        int c = ci0 + i * 4;
        int n = n0 + nj;
        if (n < NN) out[((size_t)b * CC + c0 + c) * NN + n] = tile[c * 65 + nj];
    }
}

extern "C" void kernel_launch(void* const* d_in, const int* in_sizes, int n_in,
                              void* d_out, int out_size, void* d_ws, size_t ws_size,
                              hipStream_t stream) {
    const float* x      = (const float*)d_in[0];
    const float* w1     = (const float*)d_in[1];
    const float* b1     = (const float*)d_in[2];
    const float* w2     = (const float*)d_in[3];
    const float* b2     = (const float*)d_in[4];
    const float* gamma1 = (const float*)d_in[5];
    const float* beta1  = (const float*)d_in[6];
    const float* gamma2 = (const float*)d_in[7];
    const float* beta2  = (const float*)d_in[8];
    float* out = (float*)d_out;

    const size_t BIG = (size_t)ROWS_TOTAL * CC;   // 8,294,400
    const size_t RK  = (size_t)ROWS_TOTAL * KK;   // 583,200
    float* ws   = (float*)d_ws;
    float* bufB = ws;
    f16*   xh   = (f16*)(ws + BIG);
    f16*   xl   = xh + BIG;
    float* bufA = ws + BIG;                        // ALIASES xh/xl; first written by gather1
    float* vbuf = ws + 2 * BIG;
    unsigned short* ibuf = (unsigned short*)(ws + 2 * BIG + RK);
    f16*   wth1 = (f16*)(ws + 2 * BIG + RK + RK / 2);
    f16*   wtl1 = wth1 + CC * CC;
    f16*   wth2 = wtl1 + CC * CC;
    f16*   wtl2 = wth2 + CC * CC;
    float* stats = ws + 2 * BIG + RK + RK / 2 + 2 * CC * CC;

    const int GB = (ROWS_TOTAL + 127) / 128;      // 507 gemm blocks

    k_normalize<<<dim3(32, BN), 256, 0, stream>>>(x, xh, xl);
    k_wsplit<<<2, 256, 0, stream>>>(w1, w2, wth1, wtl1, wth2, wtl2);
    k_sim_topk<<<2048, 256, 0, stream>>>(xh, xl, vbuf, ibuf);

    // layer 1 (xh/xl last read by gemm1; bufA aliases them, written by gather1 after)
    k_gemm_tile<<<GB, 256, 0, stream>>>(xh, xl, wth1, wtl1, S28, S40, bufB);
    k_gather<<<ROWS_TOTAL / 2, 256, 0, stream>>>(bufB, vbuf, ibuf, b1, bufA);
    k_gnstats<<<BN * NGROUP, 256, 0, stream>>>(bufA, stats);

    // layer 2: GN+SiLU fused into gemm2's A-staging (reads bufA + stats, writes bufB)
    k_gemm_tile_gn<<<GB, 256, 0, stream>>>(bufA, stats, gamma1, beta1, wth2, wtl2, S26, S38, bufB);
    k_gather<<<ROWS_TOTAL / 2, 256, 0, stream>>>(bufB, vbuf, ibuf, b2, bufA);
    k_gnstats<<<BN * NGROUP, 256, 0, stream>>>(bufA, stats);
    k_gnsilu_out<<<dim3((NN + 63) / 64, NGROUP, BN), 256, 0, stream>>>(bufA, stats, gamma2, beta2, out);
}

// Round 13
// 622.371 us; speedup vs baseline: 1.0791x; 1.0120x over previous
//
#include <hip/hip_runtime.h>
#include <hip/hip_bf16.h>

#define BN 32
#define CC 128
#define NN 2025
#define KK 9
#define NGROUP 4
#define CPG 32
#define GN_EPS 1e-5f
#define ROWS_TOTAL (BN * NN)   // 64800

typedef _Float16 f16;
typedef __attribute__((ext_vector_type(8))) _Float16 f16x8;
typedef __attribute__((ext_vector_type(4))) float f32x4;

#define S28 3.725290298461914e-09f   // 2^-28  (xh*wh)
#define S40 9.094947017729282e-13f   // 2^-40  (xh*wl + xl*wh)
#define S26 1.4901161193847656e-08f  // 2^-26  (vh*wh, layer2)
#define S38 3.637978807091713e-12f   // 2^-38  (vh*wl + vl*wh, layer2)

#define T0F 0.17f                    // survivor threshold (9th-best ~0.23, min ~0.19)
#define CAP 100                      // per-row survivor capacity (mean ~55, max ~95; overflow -> exact fallback)

// ---------------- Kernel 1: L2 normalize -> scaled f16 split (R10 transpose version) ----------------
__global__ __launch_bounds__(256) void k_normalize(const float* __restrict__ x,
                                                   f16* __restrict__ xh, f16* __restrict__ xl) {
    __shared__ float tile[128][65];
    const int b  = blockIdx.y;
    const int n0 = blockIdx.x * 64;
    const int t  = threadIdx.x;
    const int w  = t >> 6;
    const int lane = t & 63;
    const int gn_ld = min(n0 + lane, NN - 1);   // tail clamp (dup value, never stored)

    for (int it = 0; it < 32; ++it) {
        int c = it * 4 + w;
        tile[c][lane] = x[((size_t)(b * CC + c)) * NN + gn_ld];
    }
    __syncthreads();

    for (int i = 0; i < 16; ++i) {
        int n  = w * 16 + i;
        int gn = n0 + n;
        if (gn < NN) {
            float v0 = tile[lane][n];
            float v1 = tile[lane + 64][n];
            float ss = v0 * v0 + v1 * v1;
#pragma unroll
            for (int off = 32; off > 0; off >>= 1) ss += __shfl_xor(ss, off);
            float s = 1.0f / fmaxf(sqrtf(ss), 1e-12f);
            v0 *= s; v1 *= s;
            float w0 = v0 * 16384.0f, w1 = v1 * 16384.0f;
            f16 h0 = (f16)w0, h1 = (f16)w1;
            f16 l0 = (f16)((w0 - (float)h0) * 4096.0f);
            f16 l1 = (f16)((w1 - (float)h1) * 4096.0f);
            size_t base = (size_t)(b * NN + gn) * CC;
            xh[base + lane] = h0;  xh[base + lane + 64] = h1;
            xl[base + lane] = l0;  xl[base + lane + 64] = l1;
        }
    }
}

// top-9 insert: (value desc, index asc) ordering; order-independent tie rules — EXACT
__device__ __forceinline__ void ins9(float cand, int m, float* v, int* ix,
                                     float& mv, int& mi, int& mp) {
    bool take = (cand > mv) || ((cand == mv) && (m < mi));
    if (take) {
#pragma unroll
        for (int k = 0; k < 9; ++k) if (k == mp) { v[k] = cand; ix[k] = m; }
        float nv = v[0]; int ni = ix[0]; int np = 0;
#pragma unroll
        for (int k = 1; k < 9; ++k) {
            if (v[k] < nv || (v[k] == nv && ix[k] > ni)) { nv = v[k]; ni = ix[k]; np = k; }
        }
        mv = nv; mi = ni; mp = np;
    }
}

// ---------------- Kernel 2: fused sim + top-k (R9 structure FROZEN) ----------------
__global__ __launch_bounds__(256) void k_sim_topk(const f16* __restrict__ xh, const f16* __restrict__ xl,
                                                  float* __restrict__ vout, unsigned short* __restrict__ iout) {
    __shared__ f16x8          stg[2][32][16];  // 16KB staged 32-m window: [hl][row][frag^(row&7)]
    __shared__ float          sv[32][CAP + 1];
    __shared__ unsigned short si[32][CAP + 2];
    __shared__ int   cnt[32];
    __shared__ int   nbad;
    __shared__ int   badrows[32];

    const int id   = blockIdx.x;                  // 0..2047
    const int b    = (id & 7) + 8 * (id >> 9);
    const int r0   = ((id >> 3) & 63) * 32;
    const int t    = threadIdx.x;
    const int w    = t >> 6;
    const int lane = t & 63;
    const int jr   = lane & 15;
    const int q    = lane >> 4;
    const int tw   = w & 1;
    const int mh   = w >> 1;

    if (t < 32) cnt[t] = 0;
    if (t == 0) nbad = 0;

    f16x8 bh[4], bl[4];
    {
        int rr = b * NN + min(r0 + tw * 16 + jr, NN - 1);
        const f16* pH = xh + (size_t)rr * CC;
        const f16* pL = xl + (size_t)rr * CC;
#pragma unroll
        for (int s = 0; s < 4; ++s) {
            bh[s] = *(const f16x8*)(pH + s * 32 + q * 8);
            bl[s] = *(const f16x8*)(pL + s * 32 + q * 8);
        }
    }

    const int fi_ = t & 15;
    const int ri_ = t >> 4;
    const int fx  = fi_ ^ (ri_ & 7);
    const int rbuf = tw * 16 + jr;

    f16x8 h0r, h1r, l0r, l1r;
    {
        size_t g0 = (size_t)(b * NN + min(ri_, NN - 1)) * CC + fi_ * 8;
        size_t g1 = (size_t)(b * NN + min(ri_ + 16, NN - 1)) * CC + fi_ * 8;
        h0r = *(const f16x8*)(xh + g0);  h1r = *(const f16x8*)(xh + g1);
        l0r = *(const f16x8*)(xl + g0);  l1r = *(const f16x8*)(xl + g1);
    }

    for (int chunk = 0; chunk < 64; ++chunk) {
        __syncthreads();
        stg[0][ri_][fx]      = h0r;
        stg[0][ri_ + 16][fx] = h1r;
        stg[1][ri_][fx]      = l0r;
        stg[1][ri_ + 16][fx] = l1r;
        __syncthreads();
        if (chunk < 63) {
            size_t g0 = (size_t)(b * NN + min((chunk + 1) * 32 + ri_, NN - 1)) * CC + fi_ * 8;
            size_t g1 = (size_t)(b * NN + min((chunk + 1) * 32 + ri_ + 16, NN - 1)) * CC + fi_ * 8;
            h0r = *(const f16x8*)(xh + g0);  h1r = *(const f16x8*)(xh + g1);
            l0r = *(const f16x8*)(xl + g0);  l1r = *(const f16x8*)(xl + g1);
        }
        __builtin_amdgcn_sched_barrier(0);

        const int mb   = chunk * 32 + mh * 16;
        const int arow = mh * 16 + jr;
        const int axr  = arow & 7;
        f32x4 hh = {0.f, 0.f, 0.f, 0.f}, ll = {0.f, 0.f, 0.f, 0.f};
#pragma unroll
        for (int s = 0; s < 4; ++s) {
            f16x8 ah = stg[0][arow][(s * 4 + q) ^ axr];
            f16x8 al = stg[1][arow][(s * 4 + q) ^ axr];
            hh = __builtin_amdgcn_mfma_f32_16x16x32_f16(ah, bh[s], hh, 0, 0, 0);
            ll = __builtin_amdgcn_mfma_f32_16x16x32_f16(ah, bl[s], ll, 0, 0, 0);
            ll = __builtin_amdgcn_mfma_f32_16x16x32_f16(al, bh[s], ll, 0, 0, 0);
        }
#pragma unroll
        for (int reg = 0; reg < 4; ++reg) {
            int m = mb + q * 4 + reg;
            float c0 = hh[reg] * S28 + ll[reg] * S40;
            if (m < NN && c0 > T0F) {
                int pos = atomicAdd(&cnt[rbuf], 1);
                if (pos < CAP) { sv[rbuf][pos] = c0; si[rbuf][pos] = (unsigned short)m; }
            }
        }
    }
    __syncthreads();

    if (t < 32) {
        int r = r0 + t;
        if (r < NN) {
            int c = cnt[t];
            if (c >= 9 && c <= CAP) {
                float fv[9]; int fi[9];
#pragma unroll
                for (int k = 0; k < 9; ++k) { fv[k] = -3.0e38f; fi[k] = 0x7fffffff; }
                float mv = -3.0e38f; int mi = 0x7fffffff; int mp = 0;
                for (int j = 0; j < c; ++j) ins9(sv[t][j], (int)si[t][j], fv, fi, mv, mi, mp);
                float s = 1e-6f;
#pragma unroll
                for (int k = 0; k < 9; ++k) s += fv[k];
                float inv = 1.0f / s;
                int base = (b * NN + r) * KK;
#pragma unroll
                for (int k = 0; k < 9; ++k) { vout[base + k] = fv[k] * inv; iout[base + k] = (unsigned short)fi[k]; }
            } else {
                int slot = atomicAdd(&nbad, 1);
                badrows[slot] = r;
            }
        }
    }
    __syncthreads();

    if (w == 0) {
        int nb = nbad;
        for (int ib = 0; ib < nb; ++ib) {
            int r = badrows[ib];
            const f16* rH = xh + ((size_t)b * NN + r) * CC;
            const f16* rL = xl + ((size_t)b * NN + r) * CC;
            float fv[9]; int fi[9];
#pragma unroll
            for (int k = 0; k < 9; ++k) { fv[k] = -3.0e38f; fi[k] = 0x7fffffff; }
            float mv = -3.0e38f; int mi = 0x7fffffff; int mp = 0;
            for (int m = lane; m < NN; m += 64) {
                const f16* mH = xh + ((size_t)b * NN + m) * CC;
                const f16* mL = xl + ((size_t)b * NN + m) * CC;
                float a1 = 0.f, a2 = 0.f;
                for (int c2 = 0; c2 < CC; ++c2) {
                    float hr = (float)rH[c2], hm = (float)mH[c2];
                    float lr = (float)rL[c2], lm = (float)mL[c2];
                    a1 += hr * hm;
                    a2 += hr * lm + lr * hm;
                }
                ins9(a1 * S28 + a2 * S40, m, fv, fi, mv, mi, mp);
            }
#pragma unroll
            for (int off = 1; off < 64; off <<= 1) {
                float pv[9]; int pi[9];
#pragma unroll
                for (int k = 0; k < 9; ++k) { pv[k] = __shfl_xor(fv[k], off); pi[k] = __shfl_xor(fi[k], off); }
#pragma unroll
                for (int k = 0; k < 9; ++k) ins9(pv[k], pi[k], fv, fi, mv, mi, mp);
            }
            if (lane == 0) {
                float s = 1e-6f;
#pragma unroll
                for (int k = 0; k < 9; ++k) s += fv[k];
                float inv = 1.0f / s;
                int base = (b * NN + r) * KK;
#pragma unroll
                for (int k = 0; k < 9; ++k) { vout[base + k] = fv[k] * inv; iout[base + k] = (unsigned short)fi[k]; }
            }
        }
    }
}

// ---------------- Kernel 3pre: transpose + f16-split the weights: WT_h/WT_l in [j][c] ----------------
__global__ __launch_bounds__(256) void k_wsplit(const float* __restrict__ w1, const float* __restrict__ w2,
                                                f16* __restrict__ wth1, f16* __restrict__ wtl1,
                                                f16* __restrict__ wth2, f16* __restrict__ wtl2) {
    const float* w = blockIdx.x ? w2 : w1;
    f16* th = blockIdx.x ? wth2 : wth1;
    f16* tl = blockIdx.x ? wtl2 : wtl1;
    for (int e = threadIdx.x; e < CC * CC; e += 256) {
        int c = e >> 7, j = e & 127;
        float ws_ = w[e] * 16384.0f;
        f16 h = (f16)ws_;
        f16 l = (f16)((ws_ - (float)h) * 4096.0f);
        th[j * CC + c] = h;
        tl[j * CC + c] = l;
    }
}

// ---------------- Kernel 3: tiled MFMA split GEMM, 128 rows/block, LDS-staged A ----------------
// R13: output now f16 (value-path quantization; halves GEMM-out writes AND the
// downstream gather's 298MB random-read traffic). Selection (v/idx) already frozen.
__global__ __launch_bounds__(256) void k_gemm_tile(const f16* __restrict__ ah, const f16* __restrict__ al,
                                                   const f16* __restrict__ wth, const f16* __restrict__ wtl,
                                                   float sH, float sL, f16* __restrict__ out) {
    __shared__ f16x8 stg[2][32][16];   // [hl][row][frag^(row&7)] — sim_topk layout
    const int t    = threadIdx.x;
    const int w    = t >> 6;
    const int lane = t & 63;
    const int jr   = lane & 15;
    const int q    = lane >> 4;
    const int row0 = blockIdx.x * 128;

    f16x8 wbh[2][4], wbl[2][4];
#pragma unroll
    for (int ct = 0; ct < 2; ++ct) {
        int j = w * 32 + ct * 16 + jr;
        const f16* pH = wth + (size_t)j * CC;
        const f16* pL = wtl + (size_t)j * CC;
#pragma unroll
        for (int s = 0; s < 4; ++s) {
            wbh[ct][s] = *(const f16x8*)(pH + s * 32 + q * 8);
            wbl[ct][s] = *(const f16x8*)(pL + s * 32 + q * 8);
        }
    }

    const int fi_ = t & 15;
    const int ri_ = t >> 4;
    const int fx  = fi_ ^ (ri_ & 7);

    f16x8 h0r, h1r, l0r, l1r;
    {
        size_t g0 = (size_t)min(row0 + ri_, ROWS_TOTAL - 1) * CC + fi_ * 8;
        size_t g1 = (size_t)min(row0 + ri_ + 16, ROWS_TOTAL - 1) * CC + fi_ * 8;
        h0r = *(const f16x8*)(ah + g0);  h1r = *(const f16x8*)(ah + g1);
        l0r = *(const f16x8*)(al + g0);  l1r = *(const f16x8*)(al + g1);
    }

    for (int chunk = 0; chunk < 4; ++chunk) {
        __syncthreads();
        stg[0][ri_][fx]      = h0r;
        stg[0][ri_ + 16][fx] = h1r;
        stg[1][ri_][fx]      = l0r;
        stg[1][ri_ + 16][fx] = l1r;
        __syncthreads();
        if (chunk < 3) {
            size_t g0 = (size_t)min(row0 + (chunk + 1) * 32 + ri_, ROWS_TOTAL - 1) * CC + fi_ * 8;
            size_t g1 = (size_t)min(row0 + (chunk + 1) * 32 + ri_ + 16, ROWS_TOTAL - 1) * CC + fi_ * 8;
            h0r = *(const f16x8*)(ah + g0);  h1r = *(const f16x8*)(ah + g1);
            l0r = *(const f16x8*)(al + g0);  l1r = *(const f16x8*)(al + g1);
        }
        __builtin_amdgcn_sched_barrier(0);

#pragma unroll
        for (int rt = 0; rt < 2; ++rt) {
            const int arow = rt * 16 + jr;
            const int axr  = arow & 7;
            f16x8 af[4], alf[4];
#pragma unroll
            for (int s = 0; s < 4; ++s) {
                af[s]  = stg[0][arow][(s * 4 + q) ^ axr];
                alf[s] = stg[1][arow][(s * 4 + q) ^ axr];
            }
            f32x4 hh0 = {0.f,0.f,0.f,0.f}, ll0 = {0.f,0.f,0.f,0.f};
            f32x4 hh1 = {0.f,0.f,0.f,0.f}, ll1 = {0.f,0.f,0.f,0.f};
#pragma unroll
            for (int s = 0; s < 4; ++s) {
                hh0 = __builtin_amdgcn_mfma_f32_16x16x32_f16(af[s],  wbh[0][s], hh0, 0, 0, 0);
                ll0 = __builtin_amdgcn_mfma_f32_16x16x32_f16(af[s],  wbl[0][s], ll0, 0, 0, 0);
                ll0 = __builtin_amdgcn_mfma_f32_16x16x32_f16(alf[s], wbh[0][s], ll0, 0, 0, 0);
                hh1 = __builtin_amdgcn_mfma_f32_16x16x32_f16(af[s],  wbh[1][s], hh1, 0, 0, 0);
                ll1 = __builtin_amdgcn_mfma_f32_16x16x32_f16(af[s],  wbl[1][s], ll1, 0, 0, 0);
                ll1 = __builtin_amdgcn_mfma_f32_16x16x32_f16(alf[s], wbh[1][s], ll1, 0, 0, 0);
            }
#pragma unroll
            for (int reg = 0; reg < 4; ++reg) {
                int orow = row0 + chunk * 32 + rt * 16 + q * 4 + reg;
                if (orow < ROWS_TOTAL) {
                    size_t ob = (size_t)orow * CC + w * 32 + jr;
                    out[ob]      = (f16)(hh0[reg] * sH + ll0[reg] * sL);
                    out[ob + 16] = (f16)(hh1[reg] * sH + ll1[reg] * sL);
                }
            }
        }
    }
}

// ---------------- Kernel 3b: tiled GEMM with GN+SiLU+split fused into A-staging ----------------
// R13: act input is now f16 (gather1 output), out is f16.
__global__ __launch_bounds__(256) void k_gemm_tile_gn(const f16* __restrict__ act,
                                                      const float* __restrict__ stats,
                                                      const float* __restrict__ gamma,
                                                      const float* __restrict__ beta,
                                                      const f16* __restrict__ wth, const f16* __restrict__ wtl,
                                                      float sH, float sL, f16* __restrict__ out) {
    __shared__ f16x8 stg[2][32][16];
    const int t    = threadIdx.x;
    const int w    = t >> 6;
    const int lane = t & 63;
    const int jr   = lane & 15;
    const int q    = lane >> 4;
    const int row0 = blockIdx.x * 128;

    f16x8 wbh[2][4], wbl[2][4];
#pragma unroll
    for (int ct = 0; ct < 2; ++ct) {
        int j = w * 32 + ct * 16 + jr;
        const f16* pH = wth + (size_t)j * CC;
        const f16* pL = wtl + (size_t)j * CC;
#pragma unroll
        for (int s = 0; s < 4; ++s) {
            wbh[ct][s] = *(const f16x8*)(pH + s * 32 + q * 8);
            wbl[ct][s] = *(const f16x8*)(pL + s * 32 + q * 8);
        }
    }

    const int fi_ = t & 15;
    const int ri_ = t >> 4;
    const int fx  = fi_ ^ (ri_ & 7);
    const int gg  = fi_ >> 2;          // group of this thread's 8-channel slice

    float gma[8], bta[8];
#pragma unroll
    for (int e = 0; e < 8; ++e) { gma[e] = gamma[fi_ * 8 + e]; bta[e] = beta[fi_ * 8 + e]; }

    // preload chunk 0 rows (f16 activations)
    f16x8 pa, pb;
    int ra = min(row0 + ri_, ROWS_TOTAL - 1);
    int rb = min(row0 + ri_ + 16, ROWS_TOTAL - 1);
    pa = *(const f16x8*)(act + (size_t)ra * CC + fi_ * 8);
    pb = *(const f16x8*)(act + (size_t)rb * CC + fi_ * 8);

    for (int chunk = 0; chunk < 4; ++chunk) {
        __syncthreads();
        {
            int ba = ra / NN, bb = rb / NN;
            float ma = stats[(ba * 4 + gg) * 2], rsa = stats[(ba * 4 + gg) * 2 + 1];
            float mb = stats[(bb * 4 + gg) * 2], rsb = stats[(bb * 4 + gg) * 2 + 1];
            f16x8 hva, lva, hvb, lvb;
#pragma unroll
            for (int e = 0; e < 8; ++e) {
                float ya = ((float)pa[e] - ma) * rsa * gma[e] + bta[e];
                float ra_ = ya / (1.0f + expf(-ya));
                float sa = ra_ * 4096.0f;
                f16 h = (f16)sa; hva[e] = h; lva[e] = (f16)((sa - (float)h) * 4096.0f);
                float yb = ((float)pb[e] - mb) * rsb * gma[e] + bta[e];
                float rb_ = yb / (1.0f + expf(-yb));
                float sb = rb_ * 4096.0f;
                f16 h2 = (f16)sb; hvb[e] = h2; lvb[e] = (f16)((sb - (float)h2) * 4096.0f);
            }
            stg[0][ri_][fx]      = hva;
            stg[0][ri_ + 16][fx] = hvb;
            stg[1][ri_][fx]      = lva;
            stg[1][ri_ + 16][fx] = lvb;
        }
        __syncthreads();
        if (chunk < 3) {
            ra = min(row0 + (chunk + 1) * 32 + ri_, ROWS_TOTAL - 1);
            rb = min(row0 + (chunk + 1) * 32 + ri_ + 16, ROWS_TOTAL - 1);
            pa = *(const f16x8*)(act + (size_t)ra * CC + fi_ * 8);
            pb = *(const f16x8*)(act + (size_t)rb * CC + fi_ * 8);
        }
        __builtin_amdgcn_sched_barrier(0);

#pragma unroll
        for (int rt = 0; rt < 2; ++rt) {
            const int arow = rt * 16 + jr;
            const int axr  = arow & 7;
            f16x8 af[4], alf[4];
#pragma unroll
            for (int s = 0; s < 4; ++s) {
                af[s]  = stg[0][arow][(s * 4 + q) ^ axr];
                alf[s] = stg[1][arow][(s * 4 + q) ^ axr];
            }
            f32x4 hh0 = {0.f,0.f,0.f,0.f}, ll0 = {0.f,0.f,0.f,0.f};
            f32x4 hh1 = {0.f,0.f,0.f,0.f}, ll1 = {0.f,0.f,0.f,0.f};
#pragma unroll
            for (int s = 0; s < 4; ++s) {
                hh0 = __builtin_amdgcn_mfma_f32_16x16x32_f16(af[s],  wbh[0][s], hh0, 0, 0, 0);
                ll0 = __builtin_amdgcn_mfma_f32_16x16x32_f16(af[s],  wbl[0][s], ll0, 0, 0, 0);
                ll0 = __builtin_amdgcn_mfma_f32_16x16x32_f16(alf[s], wbh[0][s], ll0, 0, 0, 0);
                hh1 = __builtin_amdgcn_mfma_f32_16x16x32_f16(af[s],  wbh[1][s], hh1, 0, 0, 0);
                ll1 = __builtin_amdgcn_mfma_f32_16x16x32_f16(af[s],  wbl[1][s], ll1, 0, 0, 0);
                ll1 = __builtin_amdgcn_mfma_f32_16x16x32_f16(alf[s], wbh[1][s], ll1, 0, 0, 0);
            }
#pragma unroll
            for (int reg = 0; reg < 4; ++reg) {
                int orow = row0 + chunk * 32 + rt * 16 + q * 4 + reg;
                if (orow < ROWS_TOTAL) {
                    size_t ob = (size_t)orow * CC + w * 32 + jr;
                    out[ob]      = (f16)(hh0[reg] * sH + ll0[reg] * sL);
                    out[ob + 16] = (f16)(hh1[reg] * sH + ll1[reg] * sL);
                }
            }
        }
    }
}

// ---------------- Kernel 4: gather + weighted sum + bias (f16 in, f16 out) ----------------
__global__ __launch_bounds__(256) void k_gather(const f16* __restrict__ xt,
                                                const float* __restrict__ v,
                                                const unsigned short* __restrict__ idx,
                                                const float* __restrict__ bias,
                                                f16* __restrict__ out) {
    int t = threadIdx.x;
    int g = blockIdx.x * 2 + (t >> 7);
    int c = t & 127;
    if (g >= ROWS_TOTAL) return;
    int b = g / NN;
    int nb = b * NN;
    float acc = bias[c];
    int base = g * KK;
#pragma unroll
    for (int k = 0; k < KK; ++k) {
        int   ii = (int)idx[base + k];
        float vv = v[base + k];
        acc += vv * (float)xt[(size_t)(nb + ii) * CC + c];
    }
    out[(size_t)g * CC + c] = (f16)acc;
}

// ---------------- Kernel 5: GroupNorm stats per (b, group) — f16 input ----------------
__global__ __launch_bounds__(256) void k_gnstats(const f16* __restrict__ xin,
                                                 float* __restrict__ stats) {
    int bg = blockIdx.x; int b = bg >> 2; int gg = bg & 3;
    size_t base = (size_t)b * (NN * CC) + gg * CPG;
    float s1 = 0.f, s2 = 0.f;
    for (int i = threadIdx.x; i < NN * CPG; i += 256) {
        float x = (float)xin[base + (size_t)(i >> 5) * CC + (i & 31)];
        s1 += x; s2 += x * x;
    }
#pragma unroll
    for (int off = 32; off > 0; off >>= 1) { s1 += __shfl_xor(s1, off); s2 += __shfl_xor(s2, off); }
    __shared__ float r1[4], r2[4];
    int w = threadIdx.x >> 6;
    if ((threadIdx.x & 63) == 0) { r1[w] = s1; r2[w] = s2; }
    __syncthreads();
    if (threadIdx.x == 0) {
        float a = r1[0] + r1[1] + r1[2] + r1[3];
        float qq = r2[0] + r2[1] + r2[2] + r2[3];
        const float inv = 1.0f / (float)(NN * CPG);
        float mean = a * inv;
        float var = qq * inv - mean * mean;
        stats[bg * 2]     = mean;
        stats[bg * 2 + 1] = rsqrtf(fmaxf(var, 0.f) + GN_EPS);
    }
}

// ---------------- Kernel 7: GN apply + SiLU + transpose to [B][C][N] — f16 in, fp32 out ----------------
__global__ __launch_bounds__(256) void k_gnsilu_out(const f16* __restrict__ xin,
                                                    const float* __restrict__ stats,
                                                    const float* __restrict__ gamma,
                                                    const float* __restrict__ beta,
                                                    float* __restrict__ out) {
    __shared__ float tile[32 * 65];
    int b = blockIdx.z, ct = blockIdx.y, nt = blockIdx.x;
    int c0 = ct * 32, n0 = nt * 64;
    int t = threadIdx.x;
    int cj = t & 31, ni0 = t >> 5;
    int gg = c0 >> 5;
    float mean = stats[(b * 4 + gg) * 2];
    float rstd = stats[(b * 4 + gg) * 2 + 1];
    float gm = gamma[c0 + cj];
    float bt = beta[c0 + cj];
#pragma unroll
    for (int i = 0; i < 8; ++i) {
        int n = n0 + ni0 + i * 8;
        if (n < NN) {
            float x = (float)xin[((size_t)b * NN + n) * CC + c0 + cj];
            float y = (x - mean) * rstd * gm + bt;
            y = y / (1.0f + expf(-y));
            tile[cj * 65 + ni0 + i * 8] = y;
        }
    }
    __syncthreads();
    int nj = t & 63, ci0 = t >> 6;
#pragma unroll
    for (int i = 0; i < 8; ++i) {
        int c = ci0 + i * 4;
        int n = n0 + nj;
        if (n < NN) out[((size_t)b * CC + c0 + c) * NN + n] = tile[c * 65 + nj];
    }
}

extern "C" void kernel_launch(void* const* d_in, const int* in_sizes, int n_in,
                              void* d_out, int out_size, void* d_ws, size_t ws_size,
                              hipStream_t stream) {
    const float* x      = (const float*)d_in[0];
    const float* w1     = (const float*)d_in[1];
    const float* b1     = (const float*)d_in[2];
    const float* w2     = (const float*)d_in[3];
    const float* b2     = (const float*)d_in[4];
    const float* gamma1 = (const float*)d_in[5];
    const float* beta1  = (const float*)d_in[6];
    const float* gamma2 = (const float*)d_in[7];
    const float* beta2  = (const float*)d_in[8];
    float* out = (float*)d_out;

    const size_t BIG = (size_t)ROWS_TOTAL * CC;   // 8,294,400
    const size_t RK  = (size_t)ROWS_TOTAL * KK;   // 583,200
    float* ws   = (float*)d_ws;
    // Regions (floats): [bufB: BIG][xh/xl|bufA: BIG][vbuf: RK][ibuf16: RK/2][wt][stats]
    // f16 intermediates live inside the same regions (half-occupied).
    f16*   bufB_h = (f16*)ws;                      // gemm1 out / gather1 in; gemm2 out / gather2 in
    f16*   xh   = (f16*)(ws + BIG);
    f16*   xl   = xh + BIG;
    f16*   bufA_h = (f16*)(ws + BIG);              // gather1 out (aliases xh, dead after gemm1); gather2 out
    float* vbuf = ws + 2 * BIG;
    unsigned short* ibuf = (unsigned short*)(ws + 2 * BIG + RK);
    f16*   wth1 = (f16*)(ws + 2 * BIG + RK + RK / 2);
    f16*   wtl1 = wth1 + CC * CC;
    f16*   wth2 = wtl1 + CC * CC;
    f16*   wtl2 = wth2 + CC * CC;
    float* stats = ws + 2 * BIG + RK + RK / 2 + 2 * CC * CC;

    const int GB = (ROWS_TOTAL + 127) / 128;      // 507 gemm blocks

    k_normalize<<<dim3(32, BN), 256, 0, stream>>>(x, xh, xl);
    k_wsplit<<<2, 256, 0, stream>>>(w1, w2, wth1, wtl1, wth2, wtl2);
    k_sim_topk<<<2048, 256, 0, stream>>>(xh, xl, vbuf, ibuf);

    // layer 1 (xh/xl last read by gemm1; bufA_h aliases xh, written by gather1 after)
    k_gemm_tile<<<GB, 256, 0, stream>>>(xh, xl, wth1, wtl1, S28, S40, bufB_h);
    k_gather<<<ROWS_TOTAL / 2, 256, 0, stream>>>(bufB_h, vbuf, ibuf, b1, bufA_h);
    k_gnstats<<<BN * NGROUP, 256, 0, stream>>>(bufA_h, stats);

    // layer 2: GN+SiLU fused into gemm2's A-staging (reads bufA_h + stats, writes bufB_h)
    k_gemm_tile_gn<<<GB, 256, 0, stream>>>(bufA_h, stats, gamma1, beta1, wth2, wtl2, S26, S38, bufB_h);
    k_gather<<<ROWS_TOTAL / 2, 256, 0, stream>>>(bufB_h, vbuf, ibuf, b2, bufA_h);
    k_gnstats<<<BN * NGROUP, 256, 0, stream>>>(bufA_h, stats);
    k_gnsilu_out<<<dim3((NN + 63) / 64, NGROUP, BN), 256, 0, stream>>>(bufA_h, stats, gamma2, beta2, out);
}